// Round 5
// baseline (261.360 us; speedup 1.0000x reference)
//
#include <hip/hip_runtime.h>
#include <math.h>

#define N_NODES 50000
#define N_EDGES 800000
#define F_IN    128
#define F_OUT   64
#define ALPHA   0.2f

#define NP      50176              // N_NODES padded to 196*256
#define NB      196                // scan blocks

// ---------------------------------------------------------------------------
// K1: h = input @ W  (50000x128 @ 128x64), plus per-node attention scores
//     ssrc[i] = h[i,:] . a[0:64],  sdst[i] = h[i,:] . a[64:128]
// R5: 16 rows/wave, 64 rows/block -> grid = 782 blocks. LDS 33 KB caps
// residency at 4 blocks/CU = 1024 blocks chip-wide >= 782 -> ALL blocks
// co-resident, no tail round (R4's 23.8% occupancy was tail + low TLP).
// Per k4-step: 16 independent float4 loads in flight, 4 ds_read, 64 FMA.
// ---------------------------------------------------------------------------
__global__ __launch_bounds__(256) void k_gemm_scores(
    const float* __restrict__ in, const float* __restrict__ W,
    const float* __restrict__ a, float* __restrict__ h,
    float* __restrict__ ssrc, float* __restrict__ sdst) {
  __shared__ float Wl[F_IN * F_OUT];   // 32 KB, row-major [k][j]
  __shared__ float al[2 * F_OUT];

  for (int i = threadIdx.x; i < F_IN * F_OUT; i += 256) Wl[i] = W[i];
  if (threadIdx.x < 2 * F_OUT) al[threadIdx.x] = a[threadIdx.x];
  __syncthreads();                                  // only barrier in kernel

  const int wave = threadIdx.x >> 6;
  const int lane = threadIdx.x & 63;
  const int wgrp = blockIdx.x * 4 + wave;           // 16-row group id
  if (wgrp >= N_NODES / 16) return;                 // whole-wave skip (exact: 3125)
  const int row0 = wgrp * 16;

  const float* rb = in + (size_t)row0 * F_IN;
  float acc[16];
  #pragma unroll
  for (int r = 0; r < 16; ++r) acc[r] = 0.f;

  for (int k4 = 0; k4 < F_IN / 4; ++k4) {
    float4 iv[16];
    #pragma unroll
    for (int r = 0; r < 16; ++r)
      iv[r] = *reinterpret_cast<const float4*>(rb + (size_t)r * F_IN + k4 * 4);
    #pragma unroll
    for (int j = 0; j < 4; ++j) {
      const float w = Wl[(k4 * 4 + j) * F_OUT + lane];
      #pragma unroll
      for (int r = 0; r < 16; ++r)
        acc[r] += (&iv[r].x)[j] * w;
    }
  }

  #pragma unroll
  for (int r = 0; r < 16; ++r)
    h[(size_t)(row0 + r) * F_OUT + lane] = acc[r];

  const float as = al[lane], ad = al[F_OUT + lane];
  float ts[16], td[16];
  #pragma unroll
  for (int r = 0; r < 16; ++r) { ts[r] = acc[r] * as; td[r] = acc[r] * ad; }
  #pragma unroll
  for (int off = 32; off; off >>= 1) {
    #pragma unroll
    for (int r = 0; r < 16; ++r) {
      ts[r] += __shfl_xor(ts[r], off);
      td[r] += __shfl_xor(td[r], off);
    }
  }
  if (lane == 0) {
    #pragma unroll
    for (int r = 0; r < 16; ++r) {
      ssrc[row0 + r] = ts[r];
      sdst[row0 + r] = td[r];
    }
  }
}

// ---------------------------------------------------------------------------
// CSR build: histogram of src, 2-level exclusive scan, scatter {dst, ee}.
// ---------------------------------------------------------------------------
__global__ __launch_bounds__(256) void k_hist(const int* __restrict__ src,
                                              int* __restrict__ deg) {
  const int e = blockIdx.x * 256 + threadIdx.x;   // grid exact: 800000
  atomicAdd(&deg[src[e]], 1);
}

// per-block exclusive scan of 256 elements; bsum[b] = block total
__global__ __launch_bounds__(256) void k_scan_a(const int* __restrict__ deg,
                                                int* __restrict__ offs,
                                                int* __restrict__ bsum) {
  __shared__ int lds[256];
  const int i = blockIdx.x * 256 + threadIdx.x;   // deg zero-padded to NP
  const int v = deg[i];
  lds[threadIdx.x] = v;
  __syncthreads();
  #pragma unroll
  for (int off = 1; off < 256; off <<= 1) {
    int t = (threadIdx.x >= off) ? lds[threadIdx.x - off] : 0;
    __syncthreads();
    lds[threadIdx.x] += t;
    __syncthreads();
  }
  offs[i] = lds[threadIdx.x] - v;                 // exclusive within block
  if (threadIdx.x == 255) bsum[blockIdx.x] = lds[255];
}

// exclusive scan of the NB block sums (single block). bsum[NB..255] is
// POISON (0xAA) — guard the load.
__global__ __launch_bounds__(256) void k_scan_b(const int* __restrict__ bsum,
                                                int* __restrict__ boff) {
  __shared__ int lds[256];
  const int v = (threadIdx.x < NB) ? bsum[threadIdx.x] : 0;
  lds[threadIdx.x] = v;
  __syncthreads();
  #pragma unroll
  for (int off = 1; off < 256; off <<= 1) {
    int t = (threadIdx.x >= off) ? lds[threadIdx.x - off] : 0;
    __syncthreads();
    lds[threadIdx.x] += t;
    __syncthreads();
  }
  boff[threadIdx.x] = lds[threadIdx.x] - v;
}

// one thread per edge: compute ee once, place {dst, ee} in CSR slot of src
__global__ __launch_bounds__(256) void k_scatter(
    const int* __restrict__ src, const int* __restrict__ dst,
    const float* __restrict__ adj,
    const float* __restrict__ ssrc, const float* __restrict__ sdst,
    const int* __restrict__ offs, const int* __restrict__ boff,
    int* __restrict__ cursor, int2* __restrict__ pairs) {
  const int e = blockIdx.x * 256 + threadIdx.x;   // grid exact: 800000
  const int s = src[e];
  const int d = dst[e];
  const float sc = ssrc[s] + sdst[d];
  const float lr = sc > 0.f ? sc : ALPHA * sc;
  const float ee = expf(-lr) * adj[e];
  const int base = offs[s] + boff[s >> 8];
  const int pos  = base + atomicAdd(&cursor[s], 1);
  pairs[pos] = make_int2(d, __float_as_int(ee));
}

// ---------------------------------------------------------------------------
// K4: per-node gather + divide + ELU (fused epilogue). Wave per node,
// lane = feature. 4-edge unroll: ~1 KB in flight/wave x 32 waves/CU ->
// BW-bound against L2/L3 rather than latency-bound.
// ---------------------------------------------------------------------------
__global__ __launch_bounds__(256) void k_gather(
    const int2* __restrict__ pairs, const int* __restrict__ offs,
    const int* __restrict__ boff, const float* __restrict__ h,
    float* __restrict__ out) {
  const int wave = threadIdx.x >> 6;
  const int lane = threadIdx.x & 63;
  const int node = blockIdx.x * 4 + wave;         // grid exact: 12500

  const int o0 = offs[node] + boff[node >> 8];
  const int o1 = offs[node + 1] + boff[(node + 1) >> 8];

  float acc = 0.f, rs = 0.f;
  int j = o0;
  for (; j + 3 < o1; j += 4) {
    const int2 p0 = pairs[j];
    const int2 p1 = pairs[j + 1];
    const int2 p2 = pairs[j + 2];
    const int2 p3 = pairs[j + 3];
    const float h0 = h[(size_t)p0.x * F_OUT + lane];
    const float h1 = h[(size_t)p1.x * F_OUT + lane];
    const float h2 = h[(size_t)p2.x * F_OUT + lane];
    const float h3 = h[(size_t)p3.x * F_OUT + lane];
    const float e0 = __int_as_float(p0.y);
    const float e1 = __int_as_float(p1.y);
    const float e2 = __int_as_float(p2.y);
    const float e3 = __int_as_float(p3.y);
    acc += e0 * h0; rs += e0;
    acc += e1 * h1; rs += e1;
    acc += e2 * h2; rs += e2;
    acc += e3 * h3; rs += e3;
  }
  for (; j < o1; ++j) {
    const int2 p = pairs[j];
    const float ee = __int_as_float(p.y);
    acc += ee * h[(size_t)p.x * F_OUT + lane];
    rs  += ee;
  }

  float v = acc / rs;                             // deg==0 -> NaN, matches ref
  v = v > 0.f ? v : expm1f(v);
  out[(size_t)node * F_OUT + lane] = v;
}

extern "C" void kernel_launch(void* const* d_in, const int* in_sizes, int n_in,
                              void* d_out, int out_size, void* d_ws, size_t ws_size,
                              hipStream_t stream) {
  const float* input = (const float*)d_in[0];
  const float* W     = (const float*)d_in[1];
  const float* a     = (const float*)d_in[2];
  const float* adj   = (const float*)d_in[3];
  const int*   ei    = (const int*)d_in[4];
  const int*   src   = ei;
  const int*   dst   = ei + N_EDGES;
  float* out = (float*)d_out;

  // ---- workspace layout (all regions 16B-aligned) ----
  float* h    = (float*)d_ws;                        // 3.2M floats (12.8 MB)
  float* ssrc = h + (size_t)N_NODES * F_OUT;         // 50000
  float* sdst = ssrc + N_NODES;                      // 50000
  int*   deg    = (int*)(sdst + N_NODES);            // NP ints (zeroed)
  int*   cursor = deg + NP;                          // NP ints (zeroed)
  int*   offs   = cursor + NP;                       // NP ints
  int*   bsum   = offs + NP;                         // 256 ints
  int*   boff   = bsum + 256;                        // 256 ints
  int2*  pairs  = (int2*)(boff + 256);               // 800000 int2 (6.4 MB)

  hipMemsetAsync(deg, 0, 2 * NP * sizeof(int), stream);  // deg + cursor

  k_hist   <<<N_EDGES / 256, 256, 0, stream>>>(src, deg);
  k_scan_a <<<NB, 256, 0, stream>>>(deg, offs, bsum);
  k_scan_b <<<1, 256, 0, stream>>>(bsum, boff);
  k_gemm_scores<<<(N_NODES / 16 + 3) / 4, 256, 0, stream>>>(input, W, a, h, ssrc, sdst);
  k_scatter<<<N_EDGES / 256, 256, 0, stream>>>(src, dst, adj, ssrc, sdst,
                                               offs, boff, cursor, pairs);
  k_gather <<<N_NODES / 4, 256, 0, stream>>>(pairs, offs, boff, h, out);
}